// Round 1
// baseline (1953.427 us; speedup 1.0000x reference)
//
#include <hip/hip_runtime.h>
#include <hip/hip_bf16.h>

#define N_NODES  100000
#define N_EDGES  3200000
#define N_GRAPHS 1000
#define IN_DIM   10
#define HID      20
#define BN_EPS   1e-5f

// ---------------------------------------------------------------------------
// Edge scatter: agg[dst] += h[src], D channels per edge, thread per (edge,ch)
// ---------------------------------------------------------------------------
template<int D>
__global__ void scatter_kernel(const float* __restrict__ h,
                               const int* __restrict__ src,
                               const int* __restrict__ dst,
                               float* __restrict__ agg) {
    const unsigned total = (unsigned)N_EDGES * D;
    for (unsigned i = blockIdx.x * blockDim.x + threadIdx.x; i < total;
         i += gridDim.x * blockDim.x) {
        unsigned e = i / D;
        unsigned c = i - e * D;
        int s = src[e];
        int d = dst[e];
        atomicAdd(agg + (unsigned)d * D + c, h[(unsigned)s * D + c]);
    }
}

// ---------------------------------------------------------------------------
// Per-node MLP: hpre = (hin + agg) @ W + b, fused BN-stat accumulation
// (sum and sumsq per channel, wave-reduced then double atomics).
// ---------------------------------------------------------------------------
template<int DIN>
__global__ void mlp_stats_kernel(const float* __restrict__ hin,
                                 const float* __restrict__ agg,
                                 const float* __restrict__ W,   // [DIN][HID]
                                 const float* __restrict__ b,   // [HID]
                                 float* __restrict__ hpre,      // [N][HID]
                                 double* __restrict__ stats) {  // [2][HID]
    int n = blockIdx.x * blockDim.x + threadIdx.x;
    bool active = (n < N_NODES);
    float out[HID];
#pragma unroll
    for (int j = 0; j < HID; j++) out[j] = active ? b[j] : 0.0f;
    if (active) {
#pragma unroll
        for (int k = 0; k < DIN; k++) {
            float u = hin[n * DIN + k] + agg[n * DIN + k];
#pragma unroll
            for (int j = 0; j < HID; j++)
                out[j] = fmaf(u, W[k * HID + j], out[j]);
        }
#pragma unroll
        for (int j = 0; j < HID; j++) hpre[n * HID + j] = out[j];
    }
    // wave64 reduce of per-channel sum / sumsq, then one atomic per wave
    int lane = threadIdx.x & 63;
#pragma unroll
    for (int j = 0; j < HID; j++) {
        float s1 = out[j];            // inactive threads hold 0
        float s2 = s1 * s1;
        for (int off = 32; off; off >>= 1) {
            s1 += __shfl_down(s1, off);
            s2 += __shfl_down(s2, off);
        }
        if (lane == 0) {
            atomicAdd(&stats[j], (double)s1);
            atomicAdd(&stats[HID + j], (double)s2);
        }
    }
}

// ---------------------------------------------------------------------------
// Fold BN stats into per-channel scale/shift
// ---------------------------------------------------------------------------
__global__ void bn_prep_kernel(const double* __restrict__ stats,
                               const float* __restrict__ g,
                               const float* __restrict__ beta,
                               float* __restrict__ ss) {  // [2][HID]
    int c = threadIdx.x;
    if (c < HID) {
        double mu  = stats[c] / (double)N_NODES;
        double var = stats[HID + c] / (double)N_NODES - mu * mu;
        float sc = g[c] * rsqrtf((float)var + BN_EPS);
        ss[c]       = sc;
        ss[HID + c] = beta[c] - (float)mu * sc;
    }
}

// ---------------------------------------------------------------------------
// BN apply + ReLU
// ---------------------------------------------------------------------------
__global__ void bn_relu_kernel(const float* __restrict__ hpre,
                               const float* __restrict__ ss,
                               float* __restrict__ hout) {
    int i = blockIdx.x * blockDim.x + threadIdx.x;
    if (i < N_NODES * HID) {
        int c = i % HID;
        float v = fmaf(hpre[i], ss[c], ss[HID + c]);
        hout[i] = v > 0.0f ? v : 0.0f;
    }
}

// ---------------------------------------------------------------------------
// Global add pool: pooled[batch[n]] += h[n]
// ---------------------------------------------------------------------------
__global__ void pool_kernel(const float* __restrict__ h,
                            const int* __restrict__ batch,
                            float* __restrict__ pooled) {
    int i = blockIdx.x * blockDim.x + threadIdx.x;
    if (i < N_NODES * HID) {
        int n = i / HID;
        int c = i - n * HID;
        atomicAdd(pooled + batch[n] * HID + c, h[i]);
    }
}

// ---------------------------------------------------------------------------
// Final FC: out = pooled @ fcW + fcb  ([1000,20] @ [20,2])
// ---------------------------------------------------------------------------
__global__ void fc_kernel(const float* __restrict__ pooled,
                          const float* __restrict__ fcW,  // [HID][2]
                          const float* __restrict__ fcb,  // [2]
                          float* __restrict__ out) {
    int gidx = blockIdx.x * blockDim.x + threadIdx.x;
    if (gidx < N_GRAPHS) {
        float o0 = fcb[0], o1 = fcb[1];
#pragma unroll
        for (int k = 0; k < HID; k++) {
            float p = pooled[gidx * HID + k];
            o0 = fmaf(p, fcW[k * 2 + 0], o0);
            o1 = fmaf(p, fcW[k * 2 + 1], o1);
        }
        out[gidx * 2 + 0] = o0;
        out[gidx * 2 + 1] = o1;
    }
}

extern "C" void kernel_launch(void* const* d_in, const int* in_sizes, int n_in,
                              void* d_out, int out_size, void* d_ws, size_t ws_size,
                              hipStream_t stream) {
    const float* x     = (const float*)d_in[0];
    const int*   eidx  = (const int*)d_in[1];
    const int*   batch = (const int*)d_in[2];
    const float* W1 = (const float*)d_in[3];
    const float* b1 = (const float*)d_in[4];
    const float* g1 = (const float*)d_in[5];
    const float* be1 = (const float*)d_in[6];
    const float* W2 = (const float*)d_in[7];
    const float* b2 = (const float*)d_in[8];
    const float* g2 = (const float*)d_in[9];
    const float* be2 = (const float*)d_in[10];
    const float* W3 = (const float*)d_in[11];
    const float* b3 = (const float*)d_in[12];
    const float* g3 = (const float*)d_in[13];
    const float* be3 = (const float*)d_in[14];
    const float* fcW = (const float*)d_in[15];
    const float* fcb = (const float*)d_in[16];
    float* out = (float*)d_out;

    const int* src = eidx;             // edge_index[0]
    const int* dst = eidx + N_EDGES;   // edge_index[1]

    // workspace layout
    char* ws = (char*)d_ws;
    float*  agg    = (float*)(ws + 0);                         // N*20 f32 (8 MB)
    float*  hpre   = (float*)(ws + 8000000);                   // N*20 f32
    float*  hcur   = (float*)(ws + 16000000);                  // N*20 f32
    double* stats  = (double*)(ws + 24000000);                 // 40 f64
    float*  ss     = (float*)(ws + 24000512);                  // 40 f32
    float*  pooled = (float*)(ws + 24001024);                  // 1000*20 f32

    const int BLK = 256;
    const int mlp_blocks   = (N_NODES + BLK - 1) / BLK;
    const int elem_blocks  = (N_NODES * HID + BLK - 1) / BLK;
    const int scat_blocks  = 8192;

    // ----- layer 1 (DIN=10) -----
    hipMemsetAsync(agg, 0, (size_t)N_NODES * IN_DIM * sizeof(float), stream);
    hipMemsetAsync(stats, 0, 2 * HID * sizeof(double), stream);
    scatter_kernel<IN_DIM><<<scat_blocks, BLK, 0, stream>>>(x, src, dst, agg);
    mlp_stats_kernel<IN_DIM><<<mlp_blocks, BLK, 0, stream>>>(x, agg, W1, b1, hpre, stats);
    bn_prep_kernel<<<1, 64, 0, stream>>>(stats, g1, be1, ss);
    bn_relu_kernel<<<elem_blocks, BLK, 0, stream>>>(hpre, ss, hcur);

    // ----- layer 2 (DIN=20) -----
    hipMemsetAsync(agg, 0, (size_t)N_NODES * HID * sizeof(float), stream);
    hipMemsetAsync(stats, 0, 2 * HID * sizeof(double), stream);
    scatter_kernel<HID><<<scat_blocks, BLK, 0, stream>>>(hcur, src, dst, agg);
    mlp_stats_kernel<HID><<<mlp_blocks, BLK, 0, stream>>>(hcur, agg, W2, b2, hpre, stats);
    bn_prep_kernel<<<1, 64, 0, stream>>>(stats, g2, be2, ss);
    bn_relu_kernel<<<elem_blocks, BLK, 0, stream>>>(hpre, ss, hcur);

    // ----- layer 3 (DIN=20) -----
    hipMemsetAsync(agg, 0, (size_t)N_NODES * HID * sizeof(float), stream);
    hipMemsetAsync(stats, 0, 2 * HID * sizeof(double), stream);
    scatter_kernel<HID><<<scat_blocks, BLK, 0, stream>>>(hcur, src, dst, agg);
    mlp_stats_kernel<HID><<<mlp_blocks, BLK, 0, stream>>>(hcur, agg, W3, b3, hpre, stats);
    bn_prep_kernel<<<1, 64, 0, stream>>>(stats, g3, be3, ss);
    bn_relu_kernel<<<elem_blocks, BLK, 0, stream>>>(hpre, ss, hcur);

    // ----- pool + FC -----
    hipMemsetAsync(pooled, 0, (size_t)N_GRAPHS * HID * sizeof(float), stream);
    pool_kernel<<<elem_blocks, BLK, 0, stream>>>(hcur, batch, pooled);
    fc_kernel<<<(N_GRAPHS + BLK - 1) / BLK, BLK, 0, stream>>>(pooled, fcW, fcb, out);
}

// Round 2
// 839.983 us; speedup vs baseline: 2.3256x; 2.3256x over previous
//
#include <hip/hip_runtime.h>
#include <hip/hip_bf16.h>

#define N_NODES  100000
#define N_EDGES  3200000
#define N_GRAPHS 1000
#define IN_DIM   10
#define HID      20
#define BN_EPS   1e-5f
#define NBLK     ((N_NODES + 255) / 256)   // 391 blocks for node-parallel kernels

// ---------------------------------------------------------------------------
// CSR build: histogram of dst
// ---------------------------------------------------------------------------
__global__ void hist_kernel(const int* __restrict__ dst, int* __restrict__ deg) {
    int e = blockIdx.x * blockDim.x + threadIdx.x;
    if (e < N_EDGES) atomicAdd(&deg[dst[e]], 1);
}

// exclusive scan, 3 kernels ------------------------------------------------
__global__ void scan_k1(const int* __restrict__ deg, int* __restrict__ rp,
                        int* __restrict__ bsum) {
    __shared__ int lds[256];
    int t = threadIdx.x;
    int idx = blockIdx.x * 256 + t;
    int v = (idx < N_NODES) ? deg[idx] : 0;
    int val = v;
    lds[t] = val; __syncthreads();
    for (int off = 1; off < 256; off <<= 1) {
        int add = (t >= off) ? lds[t - off] : 0;
        __syncthreads();
        val += add; lds[t] = val;
        __syncthreads();
    }
    if (idx < N_NODES) rp[idx] = val - v;      // block-local exclusive
    if (t == 255) bsum[blockIdx.x] = val;      // block total
}

__global__ void scan_k2(int* __restrict__ bsum) {   // in-place exclusive, 512 thr
    __shared__ int lds[512];
    int t = threadIdx.x;
    int v = (t < NBLK) ? bsum[t] : 0;
    int val = v;
    lds[t] = val; __syncthreads();
    for (int off = 1; off < 512; off <<= 1) {
        int add = (t >= off) ? lds[t - off] : 0;
        __syncthreads();
        val += add; lds[t] = val;
        __syncthreads();
    }
    if (t < NBLK) bsum[t] = val - v;
}

__global__ void scan_k3(int* __restrict__ rp, const int* __restrict__ bsum) {
    int idx = blockIdx.x * 256 + threadIdx.x;
    if (idx < N_NODES) rp[idx] += bsum[blockIdx.x];
    if (idx == 0) rp[N_NODES] = N_EDGES;
}

// fill: consumes deg (atomicSub), writes csr_src --------------------------
__global__ void fill_kernel(const int* __restrict__ src, const int* __restrict__ dst,
                            const int* __restrict__ rp, int* __restrict__ deg,
                            int* __restrict__ csr) {
    int e = blockIdx.x * blockDim.x + threadIdx.x;
    if (e < N_EDGES) {
        int d = dst[e];
        int slot = atomicSub(&deg[d], 1) - 1;   // unique in [0, deg)
        csr[rp[d] + slot] = src[e];
    }
}

// ---------------------------------------------------------------------------
// Fused: CSR gather + (h + agg) @ W + b  + BN-stat block partials
// ---------------------------------------------------------------------------
template<int DIN>
__global__ __launch_bounds__(256) void gather_mlp(
        const float* __restrict__ h,
        const int* __restrict__ rp, const int* __restrict__ csr,
        const float* __restrict__ W,   // [DIN][HID]
        const float* __restrict__ b,   // [HID]
        float* __restrict__ hpre,      // [N][HID]
        float* __restrict__ partials)  // [NBLK][2*HID]
{
    int n = blockIdx.x * 256 + threadIdx.x;
    float u[DIN];
    float out[HID];
    if (n < N_NODES) {
        if constexpr (DIN == 20) {
            const float4* hv = (const float4*)h + n * 5;
#pragma unroll
            for (int q = 0; q < 5; q++) {
                float4 a = hv[q];
                u[4*q] = a.x; u[4*q+1] = a.y; u[4*q+2] = a.z; u[4*q+3] = a.w;
            }
        } else {
            const float2* hv = (const float2*)h + n * 5;
#pragma unroll
            for (int q = 0; q < 5; q++) {
                float2 a = hv[q];
                u[2*q] = a.x; u[2*q+1] = a.y;
            }
        }
        int e0 = rp[n], e1 = rp[n + 1];
#pragma unroll 2
        for (int e = e0; e < e1; e++) {
            int s = csr[e];
            if constexpr (DIN == 20) {
                const float4* sv = (const float4*)h + s * 5;
#pragma unroll
                for (int q = 0; q < 5; q++) {
                    float4 a = sv[q];
                    u[4*q] += a.x; u[4*q+1] += a.y; u[4*q+2] += a.z; u[4*q+3] += a.w;
                }
            } else {
                const float2* sv = (const float2*)h + s * 5;
#pragma unroll
                for (int q = 0; q < 5; q++) {
                    float2 a = sv[q];
                    u[2*q] += a.x; u[2*q+1] += a.y;
                }
            }
        }
#pragma unroll
        for (int j = 0; j < HID; j++) out[j] = b[j];
#pragma unroll
        for (int k = 0; k < DIN; k++)
#pragma unroll
            for (int j = 0; j < HID; j++)
                out[j] = fmaf(u[k], W[k * HID + j], out[j]);
        float4* ov = (float4*)(hpre + (size_t)n * HID);
#pragma unroll
        for (int q = 0; q < 5; q++) {
            float4 a; a.x = out[4*q]; a.y = out[4*q+1]; a.z = out[4*q+2]; a.w = out[4*q+3];
            ov[q] = a;
        }
    } else {
#pragma unroll
        for (int j = 0; j < HID; j++) out[j] = 0.0f;
    }
    // block reduce: wave shuffle -> LDS across 4 waves -> per-block partials
    int lane = threadIdx.x & 63;
    int wave = threadIdx.x >> 6;
    __shared__ float red[4][2 * HID];
#pragma unroll
    for (int j = 0; j < HID; j++) {
        float s1 = out[j];
        float s2 = s1 * s1;
        for (int off = 32; off; off >>= 1) {
            s1 += __shfl_down(s1, off);
            s2 += __shfl_down(s2, off);
        }
        if (lane == 0) { red[wave][j] = s1; red[wave][HID + j] = s2; }
    }
    __syncthreads();
    int t = threadIdx.x;
    if (t < 2 * HID) {
        float s = red[0][t] + red[1][t] + red[2][t] + red[3][t];
        partials[blockIdx.x * (2 * HID) + t] = s;
    }
}

// ---------------------------------------------------------------------------
// Reduce partials (f64) -> per-channel scale/shift
// ---------------------------------------------------------------------------
__global__ void bn_prep_kernel(const float* __restrict__ partials,
                               const float* __restrict__ g,
                               const float* __restrict__ beta,
                               float* __restrict__ ss) {
    __shared__ double sums[2 * HID];
    int t = threadIdx.x;
    if (t < 2 * HID) {
        double acc = 0.0;
        for (int bidx = 0; bidx < NBLK; bidx++)
            acc += (double)partials[bidx * (2 * HID) + t];
        sums[t] = acc;
    }
    __syncthreads();
    if (t < HID) {
        double mu  = sums[t] / (double)N_NODES;
        double var = sums[HID + t] / (double)N_NODES - mu * mu;
        float sc = g[t] * (float)(1.0 / sqrt(var + (double)BN_EPS));
        ss[t]       = sc;
        ss[HID + t] = beta[t] - (float)mu * sc;
    }
}

// ---------------------------------------------------------------------------
// BN apply + ReLU, float4
// ---------------------------------------------------------------------------
__global__ void bn_relu_kernel(const float4* __restrict__ hpre4,
                               const float* __restrict__ ss,
                               float4* __restrict__ hout4) {
    __shared__ float s_ss[2 * HID];
    if (threadIdx.x < 2 * HID) s_ss[threadIdx.x] = ss[threadIdx.x];
    __syncthreads();
    int i = blockIdx.x * blockDim.x + threadIdx.x;
    if (i < N_NODES * HID / 4) {
        int c0 = (i % 5) * 4;
        float4 v = hpre4[i];
        v.x = fmaf(v.x, s_ss[c0 + 0], s_ss[HID + c0 + 0]); v.x = v.x > 0.f ? v.x : 0.f;
        v.y = fmaf(v.y, s_ss[c0 + 1], s_ss[HID + c0 + 1]); v.y = v.y > 0.f ? v.y : 0.f;
        v.z = fmaf(v.z, s_ss[c0 + 2], s_ss[HID + c0 + 2]); v.z = v.z > 0.f ? v.z : 0.f;
        v.w = fmaf(v.w, s_ss[c0 + 3], s_ss[HID + c0 + 3]); v.w = v.w > 0.f ? v.w : 0.f;
        hout4[i] = v;
    }
}

// ---------------------------------------------------------------------------
// graph_ptr from sorted batch (handles empty graphs)
// ---------------------------------------------------------------------------
__global__ void gptr_kernel(const int* __restrict__ batch, int* __restrict__ gptr) {
    int n = blockIdx.x * blockDim.x + threadIdx.x;
    if (n >= N_NODES) return;
    int g = batch[n];
    int gp = (n == 0) ? -1 : batch[n - 1];
    for (int q = gp + 1; q <= g; q++) gptr[q] = n;
    if (n == N_NODES - 1)
        for (int q = g + 1; q <= N_GRAPHS; q++) gptr[q] = N_NODES;
}

// ---------------------------------------------------------------------------
// Pool: thread per (graph, channel), segment sum (batch sorted -> contiguous)
// ---------------------------------------------------------------------------
__global__ void pool_kernel(const float* __restrict__ h,
                            const int* __restrict__ gptr,
                            float* __restrict__ pooled) {
    int t = blockIdx.x * blockDim.x + threadIdx.x;
    if (t < N_GRAPHS * HID) {
        int g = t / HID, c = t - g * HID;
        int n0 = gptr[g], n1 = gptr[g + 1];
        float s = 0.0f;
        for (int n = n0; n < n1; n++) s += h[(size_t)n * HID + c];
        pooled[t] = s;
    }
}

// ---------------------------------------------------------------------------
// Final FC: [1000,20] @ [20,2] + b
// ---------------------------------------------------------------------------
__global__ void fc_kernel(const float* __restrict__ pooled,
                          const float* __restrict__ fcW,
                          const float* __restrict__ fcb,
                          float* __restrict__ out) {
    int gidx = blockIdx.x * blockDim.x + threadIdx.x;
    if (gidx < N_GRAPHS) {
        float o0 = fcb[0], o1 = fcb[1];
#pragma unroll
        for (int k = 0; k < HID; k++) {
            float p = pooled[gidx * HID + k];
            o0 = fmaf(p, fcW[k * 2 + 0], o0);
            o1 = fmaf(p, fcW[k * 2 + 1], o1);
        }
        out[gidx * 2 + 0] = o0;
        out[gidx * 2 + 1] = o1;
    }
}

extern "C" void kernel_launch(void* const* d_in, const int* in_sizes, int n_in,
                              void* d_out, int out_size, void* d_ws, size_t ws_size,
                              hipStream_t stream) {
    const float* x     = (const float*)d_in[0];
    const int*   eidx  = (const int*)d_in[1];
    const int*   batch = (const int*)d_in[2];
    const float* W1 = (const float*)d_in[3];
    const float* b1 = (const float*)d_in[4];
    const float* g1 = (const float*)d_in[5];
    const float* be1 = (const float*)d_in[6];
    const float* W2 = (const float*)d_in[7];
    const float* b2 = (const float*)d_in[8];
    const float* g2 = (const float*)d_in[9];
    const float* be2 = (const float*)d_in[10];
    const float* W3 = (const float*)d_in[11];
    const float* b3 = (const float*)d_in[12];
    const float* g3 = (const float*)d_in[13];
    const float* be3 = (const float*)d_in[14];
    const float* fcW = (const float*)d_in[15];
    const float* fcb = (const float*)d_in[16];
    float* out = (float*)d_out;

    const int* src = eidx;
    const int* dst = eidx + N_EDGES;

    // workspace layout (bytes)
    char* ws = (char*)d_ws;
    int*   csr     = (int*)(ws + 0);            // 12,800,000
    int*   rp      = (int*)(ws + 12800000);     // 400,004
    int*   deg     = (int*)(ws + 13200128);     // 400,000
    float* hpre    = (float*)(ws + 13600256);   // 8,000,000
    float* hcur    = (float*)(ws + 21600256);   // 8,000,000
    float* partials= (float*)(ws + 29600256);   // 391*40*4 = 62,560
    int*   bsum    = (int*)(ws + 29662848);     // 1,564
    float* ss      = (float*)(ws + 29664512);   // 160
    int*   gptr    = (int*)(ws + 29664768);     // 4,004
    float* pooled  = (float*)(ws + 29668864);   // 80,000

    const int BLK = 256;
    const int edge_blocks = (N_EDGES + BLK - 1) / BLK;

    // ---- CSR build (once, reused by all 3 layers) ----
    hipMemsetAsync(deg, 0, (size_t)N_NODES * sizeof(int), stream);
    hist_kernel<<<edge_blocks, BLK, 0, stream>>>(dst, deg);
    scan_k1<<<NBLK, 256, 0, stream>>>(deg, rp, bsum);
    scan_k2<<<1, 512, 0, stream>>>(bsum);
    scan_k3<<<NBLK, 256, 0, stream>>>(rp, bsum);
    fill_kernel<<<edge_blocks, BLK, 0, stream>>>(src, dst, rp, deg, csr);

    const int elem4_blocks = (N_NODES * HID / 4 + BLK - 1) / BLK;

    // ---- layer 1 (DIN=10) ----
    gather_mlp<IN_DIM><<<NBLK, 256, 0, stream>>>(x, rp, csr, W1, b1, hpre, partials);
    bn_prep_kernel<<<1, 64, 0, stream>>>(partials, g1, be1, ss);
    bn_relu_kernel<<<elem4_blocks, BLK, 0, stream>>>((const float4*)hpre, ss, (float4*)hcur);

    // ---- layer 2 (DIN=20) ----
    gather_mlp<HID><<<NBLK, 256, 0, stream>>>(hcur, rp, csr, W2, b2, hpre, partials);
    bn_prep_kernel<<<1, 64, 0, stream>>>(partials, g2, be2, ss);
    bn_relu_kernel<<<elem4_blocks, BLK, 0, stream>>>((const float4*)hpre, ss, (float4*)hcur);

    // ---- layer 3 (DIN=20) ----
    gather_mlp<HID><<<NBLK, 256, 0, stream>>>(hcur, rp, csr, W3, b3, hpre, partials);
    bn_prep_kernel<<<1, 64, 0, stream>>>(partials, g3, be3, ss);
    bn_relu_kernel<<<elem4_blocks, BLK, 0, stream>>>((const float4*)hpre, ss, (float4*)hcur);

    // ---- pool + FC ----
    gptr_kernel<<<NBLK, 256, 0, stream>>>(batch, gptr);
    pool_kernel<<<(N_GRAPHS * HID + BLK - 1) / BLK, BLK, 0, stream>>>(hcur, gptr, pooled);
    fc_kernel<<<(N_GRAPHS + BLK - 1) / BLK, BLK, 0, stream>>>(pooled, fcW, fcb, out);
}